// Round 6
// baseline (301.010 us; speedup 1.0000x reference)
//
#include <hip/hip_runtime.h>

// ---------------------------------------------------------------------------
// DistanceLoss pipeline on MI355X (gfx950)
//
// R4: tuple-gather factored out of embed GEMM (Y = X@Wsplit^T, 16.8 GFLOP).
// R5: contrast as per-(class,row) wave dot products.
// R6: GEMM K-loop software-pipelined: 3-stage LDS ring, raw s_barrier +
//     s_waitcnt vmcnt(4) (tile k+2 stays in flight across the barrier);
//     stats -> wave-per-row; 9 launches (prep fused, msum/dmax folded).
//
//  1. prep: W fp32->split bf16 [4096x2048]; X bf16 [1024x2048]; zero record/msum
//  2. gemm_bt epi=2: Y = X @ Wsplit^T, fp32 [1024x4096]
//  3. build_e: E rows (bf16) + row norms sq
//  4. gemm_bt epi=1: D[i][j] = dist(E[i],E[3375+j]) [4608x1152]
//  5. stats_wave: per-(c,i) rowmax/argmax/group-max (1 wave per row)
//  6. record_part / record_finish(+msum)
//  7. contrast_rows / final_kernel(dmax + logits)
// ---------------------------------------------------------------------------

typedef __bf16 bf16x8 __attribute__((ext_vector_type(8)));
typedef float f32x4 __attribute__((ext_vector_type(4)));

#define NQT   3375      // 75*45 query-tuple rows
#define MROWS 4500      // 3375 query rows + 1125 support rows
#define MPAD  4608      // 36 * 128
#define K2    2048
#define LDD   1152      // padded 1125 -> 9*128
#define BK    32        // K-tile; LDS stride = 32 (UNPADDED: required by global_load_lds)

__constant__ int P0[45] = {0,0,0,0,0,0,0,0,0,
                           1,1,1,1,1,1,1,1,
                           2,2,2,2,2,2,2,
                           3,3,3,3,3,3,
                           4,4,4,4,4,
                           5,5,5,5,
                           6,6,6,
                           7,7,
                           8};
__constant__ int P1[45] = {1,2,3,4,5,6,7,8,9,
                           2,3,4,5,6,7,8,9,
                           3,4,5,6,7,8,9,
                           4,5,6,7,8,9,
                           5,6,7,8,9,
                           6,7,8,9,
                           7,8,9,
                           8,9,
                           9};

__device__ inline unsigned short f2b(float x) {
  __bf16 b = (__bf16)x;               // RNE
  return __builtin_bit_cast(unsigned short, b);
}
__device__ inline float b2f(unsigned int u16) {
  return __uint_as_float(u16 << 16);
}

// async global->LDS, 16B per lane; lds dest must be wave-uniform base + lane*16
__device__ __forceinline__ void gl_lds16(const unsigned short* g, unsigned short* l) {
  __builtin_amdgcn_global_load_lds(
      (__attribute__((address_space(1))) void*)(g),
      (__attribute__((address_space(3))) void*)(l),
      16, 0, 0);
}

// ---- 1: prep: conv W (split) + conv X + zero record/msum -------------------
__global__ void prep(const float* __restrict__ W, const float* __restrict__ Q,
                     const float* __restrict__ Sp,
                     unsigned short* __restrict__ Ws, unsigned short* __restrict__ X,
                     float* __restrict__ record, float* __restrict__ msum) {
  int b = blockIdx.x, tid = threadIdx.x;
  if (b < 8192) {                                    // W -> split bf16
    int i = b * 256 + tid;
    int i4 = i << 2;
    int o  = i4 >> 12;
    int k  = i4 & 4095;
    int hf = k >> 11;
    int kk = k & 2047;
    float4 v = reinterpret_cast<const float4*>(W)[i];
    ushort4 u;
    u.x = f2b(v.x); u.y = f2b(v.y); u.z = f2b(v.z); u.w = f2b(v.w);
    *reinterpret_cast<ushort4*>(Ws + (size_t)(o + hf * 2048) * 2048 + kk) = u;
  } else if (b < 10240) {                            // X = bf16(Q || S), pad 0
    int i = (b - 8192) * 256 + tid;
    ushort4 u = {0, 0, 0, 0};
    if (i < 384000) {                                // 750*2048/4
      float4 v = reinterpret_cast<const float4*>(Q)[i];
      u.x = f2b(v.x); u.y = f2b(v.y); u.z = f2b(v.z); u.w = f2b(v.w);
    } else if (i < 512000) {                         // + 250*2048/4
      float4 v = reinterpret_cast<const float4*>(Sp)[i - 384000];
      u.x = f2b(v.x); u.y = f2b(v.y); u.z = f2b(v.z); u.w = f2b(v.w);
    }
    reinterpret_cast<ushort4*>(X)[i] = u;
  } else {                                           // zero record + msum
    int i = (b - 10240) * 256 + tid;
    if (i < 4500) record[i] = 0.f;
    else if (i < 4505) msum[i - 4500] = 0.f;
  }
}

// ---- 2/4: bf16 MFMA GEMM, C = A @ B^T, 128x128 tile, BK=32 -----------------
// 3-stage pipelined global_load_lds; chunk-XOR swizzle in LDS.
// epi==1: Dout[row*ldd+col] = sqrt(max(0, sq[row] + sq[3375+col] - 2*acc))
// epi==2: Dout[row*ldd+col] = acc (fp32)
__global__ __launch_bounds__(256)
void gemm_bt(const unsigned short* __restrict__ A, const unsigned short* __restrict__ B,
             int K, int lda, int ldb, int epi,
             const float* __restrict__ sq,
             float* __restrict__ Dout, int ldd) {
  __shared__ unsigned short As[3][128 * BK];   // 3 x 8 KB
  __shared__ unsigned short Bs[3][128 * BK];
  const int tid  = threadIdx.x;
  const int wave = tid >> 6, lane = tid & 63;
  const int quad = lane >> 4, l16 = lane & 15;
  const int wm = (wave >> 1) * 64, wn = (wave & 1) * 64;
  const int m0 = blockIdx.x * 128, n0 = blockIdx.y * 128;

  f32x4 acc[4][4];
#pragma unroll
  for (int i = 0; i < 4; ++i)
#pragma unroll
    for (int j = 0; j < 4; ++j) {
      f32x4 z = {0.f, 0.f, 0.f, 0.f};
      acc[i][j] = z;
    }

  const int r0  = tid >> 2;                          // 0..63
  const int qsw = (tid & 3) ^ ((tid >> 3) & 3);      // swizzled global chunk
  const int kp0 = qsw * 8;
  const int rsw = (quad ^ ((l16 >> 1) & 3)) * 8;     // conflict-free read slot
  const unsigned short* pa0 = A + (size_t)(m0 + r0) * lda + kp0;
  const unsigned short* pa1 = A + (size_t)(m0 + r0 + 64) * lda + kp0;
  const unsigned short* pb0 = B + (size_t)(n0 + r0) * ldb + kp0;
  const unsigned short* pb1 = B + (size_t)(n0 + r0 + 64) * ldb + kp0;
  const int NKi = K / BK;

#define ISSUE(kk, st) do {                                   \
    gl_lds16(pa0 + (size_t)(kk) * BK, &As[st][wave * 512]);        \
    gl_lds16(pa1 + (size_t)(kk) * BK, &As[st][2048 + wave * 512]); \
    gl_lds16(pb0 + (size_t)(kk) * BK, &Bs[st][wave * 512]);        \
    gl_lds16(pb1 + (size_t)(kk) * BK, &Bs[st][2048 + wave * 512]); \
  } while (0)

  ISSUE(0, 0);
  ISSUE(1, 1);
  asm volatile("s_waitcnt vmcnt(4)" ::: "memory");   // tile 0 resident
  __builtin_amdgcn_s_barrier();

  int sc = 0;
  for (int k = 0; k < NKi; ++k) {
    int sn = sc + 2; if (sn >= 3) sn -= 3;
    if (k + 2 < NKi) ISSUE(k + 2, sn);               // stays in flight across barrier
    bf16x8 af[4], bfr[4];
#pragma unroll
    for (int t = 0; t < 4; ++t)
      af[t] = *reinterpret_cast<const bf16x8*>(&As[sc][(wm + t * 16 + l16) * BK + rsw]);
#pragma unroll
    for (int t = 0; t < 4; ++t)
      bfr[t] = *reinterpret_cast<const bf16x8*>(&Bs[sc][(wn + t * 16 + l16) * BK + rsw]);
#pragma unroll
    for (int i = 0; i < 4; ++i)
#pragma unroll
      for (int j = 0; j < 4; ++j)
        acc[i][j] = __builtin_amdgcn_mfma_f32_16x16x32_bf16(af[i], bfr[j], acc[i][j], 0, 0, 0);
    if (k + 1 < NKi) {
      if (k + 2 < NKi) asm volatile("s_waitcnt vmcnt(4)" ::: "memory");  // tile k+1 done
      else             asm volatile("s_waitcnt vmcnt(0)" ::: "memory");
      __builtin_amdgcn_s_barrier();
    }
    sc = sc + 1; if (sc >= 3) sc = 0;
  }
#undef ISSUE

  // epilogue: C/D layout col=lane&15, row=quad*4+reg
  if (epi == 2) {
#pragma unroll
    for (int i = 0; i < 4; ++i)
#pragma unroll
      for (int j = 0; j < 4; ++j) {
        int col = n0 + wn + j * 16 + l16;
        int rbase = m0 + wm + i * 16 + quad * 4;
        f32x4 v = acc[i][j];
#pragma unroll
        for (int r = 0; r < 4; ++r)
          Dout[(size_t)(rbase + r) * ldd + col] = v[r];
      }
  } else {
#pragma unroll
    for (int i = 0; i < 4; ++i)
#pragma unroll
      for (int j = 0; j < 4; ++j) {
        int col = n0 + wn + j * 16 + l16;
        int rbase = m0 + wm + i * 16 + quad * 4;
        float sc2 = sq[NQT + col];
        f32x4 v = acc[i][j];
#pragma unroll
        for (int r = 0; r < 4; ++r) {
          float x = sq[rbase + r] + sc2 - 2.f * v[r];
          Dout[(size_t)(rbase + r) * ldd + col] = sqrtf(fmaxf(x, 0.f));
        }
      }
  }
}

// ---- 3: E rows from Y (gather-add-relu-bf16) + row norms -------------------
__global__ void build_e(const float* __restrict__ Y, const float* __restrict__ bias,
                        unsigned short* __restrict__ E, float* __restrict__ sq) {
  int r = blockIdx.x, tid = threadIdx.x;
  if (r >= MROWS) {                    // pad rows: zeros
    uint4 z = {0, 0, 0, 0};
    reinterpret_cast<uint4*>(E + (size_t)r * 2048)[tid] = z;
    if (tid == 0) sq[r] = 0.f;
    return;
  }
  int x0, x1;
  if (r < NQT) {
    int n = r / 45, t = r - n * 45;
    x0 = n * 10 + P0[t]; x1 = n * 10 + P1[t];
  } else {
    int rr = r - NQT;
    int c = rr / 225, j = rr - c * 225;
    int sh = j / 45, t = j - sh * 45;
    int s = 750 + (c * 5 + sh) * 10;
    x0 = s + P0[t]; x1 = s + P1[t];
  }
  const float4* y0 = reinterpret_cast<const float4*>(Y + (size_t)x0 * 4096) + tid * 2;
  const float4* y1 = reinterpret_cast<const float4*>(Y + (size_t)x1 * 4096 + 2048) + tid * 2;
  const float4* bz = reinterpret_cast<const float4*>(bias) + tid * 2;
  float s = 0.f;
  unsigned short o[8];
#pragma unroll
  for (int h = 0; h < 2; ++h) {
    float4 a = y0[h], b = y1[h], c = bz[h];
    float v[4] = {a.x + b.x + c.x, a.y + b.y + c.y, a.z + b.z + c.z, a.w + b.w + c.w};
#pragma unroll
    for (int u = 0; u < 4; ++u) {
      float x = fmaxf(v[u], 0.f);
      unsigned short ob = f2b(x);
      o[h * 4 + u] = ob;
      float xr = b2f(ob);
      s += xr * xr;                    // norm from rounded value
    }
  }
  reinterpret_cast<uint4*>(E + (size_t)r * 2048)[tid] = *reinterpret_cast<uint4*>(o);
  __shared__ float red[256];
  red[tid] = s;
  __syncthreads();
  for (int st = 128; st > 0; st >>= 1) {
    if (tid < st) red[tid] += red[tid + st];
    __syncthreads();
  }
  if (tid == 0) sq[r] = red[0];
}

// ---- 5: stats, one wave per (c,i) ------------------------------------------
__global__ __launch_bounds__(256)
void stats_wave(const float* __restrict__ D, float* __restrict__ ave,
                int* __restrict__ pos, float* __restrict__ rmax) {
  int wave = threadIdx.x >> 6, lane = threadIdx.x & 63;
  int i = blockIdx.x * 4 + wave;
  int c = blockIdx.y;
  if (i >= NQT) return;
  const float* p = D + (size_t)i * LDD + c * 225;
  float best = -1e30f; int bi = 225;
  float gm5[5] = {-1e30f, -1e30f, -1e30f, -1e30f, -1e30f};
#pragma unroll
  for (int r = 0; r < 4; ++r) {
    int j = r * 64 + lane;
    if (j < 225) {
      float v = p[j];
      if (v > best) { best = v; bi = j; }            // first-occurrence (j asc)
      gm5[j % 5] = fmaxf(gm5[j % 5], v);
    }
  }
#pragma unroll
  for (int s = 32; s > 0; s >>= 1) {
    float vv = __shfl_down(best, s, 64);
    int   ii = __shfl_down(bi,   s, 64);
    if (vv > best || (vv == best && ii < bi)) { best = vv; bi = ii; }
  }
#pragma unroll
  for (int g = 0; g < 5; ++g)
#pragma unroll
    for (int s = 32; s > 0; s >>= 1)
      gm5[g] = fmaxf(gm5[g], __shfl_down(gm5[g], s, 64));
  if (lane == 0) {
    ave[c * NQT + i]  = (gm5[0] + gm5[1] + gm5[2] + gm5[3] + gm5[4]) * 0.2f;
    pos[c * NQT + i]  = bi;
    rmax[c * NQT + i] = best;
  }
}

// ---- 6a: record counts, parallel over query chunks -------------------------
__global__ void record_part(const float* __restrict__ D, const float* __restrict__ ave,
                            const int* __restrict__ pos, float* __restrict__ record) {
  int b = blockIdx.x;
  int c = b / 27, chunk = b - c * 27;
  int i0 = chunk * 125;
  int tid = threadIdx.x;
  __shared__ int   sp[125];
  __shared__ float sa[125];
  if (tid < 125) {
    sp[tid] = pos[c * NQT + i0 + tid];
    sa[tid] = ave[c * NQT + i0 + tid];
  }
  __syncthreads();
  float cnt[4] = {0.f, 0.f, 0.f, 0.f};
  int gcol[4];
#pragma unroll
  for (int j = 0; j < 4; ++j) {
    int col = tid + j * 256;
    gcol[j] = (col < 900) ? (col < c * 225 ? col : col + 225) : 0;
  }
  const bool act3 = (tid + 768) < 900;
  const float* Dsup = D + (size_t)(NQT + c * 225) * LDD;
  for (int ii = 0; ii < 125; ++ii) {
    const float* row = Dsup + (size_t)sp[ii] * LDD;
    float a = sa[ii];
    cnt[0] += (row[gcol[0]] > a) ? 1.f : 0.f;
    cnt[1] += (row[gcol[1]] > a) ? 1.f : 0.f;
    cnt[2] += (row[gcol[2]] > a) ? 1.f : 0.f;
    if (act3) cnt[3] += (row[gcol[3]] > a) ? 1.f : 0.f;
  }
#pragma unroll
  for (int j = 0; j < 4; ++j) {
    int col = tid + j * 256;
    if (col < 900) atomicAdd(&record[c * 900 + col], cnt[j]);
  }
}

// ---- 6b: thr + mask + msum partial ----------------------------------------
__global__ void record_finish(const float* __restrict__ record, float* __restrict__ mask,
                              float* __restrict__ msum) {
  int b = blockIdx.x;                 // 0..19
  int c = b / 4, mi = b - c * 4;
  int tid = threadIdx.x;
  float r = (tid < 225) ? record[c * 900 + mi * 225 + tid] : 0.f;
  __shared__ float s1[256], s2[256];
  __shared__ float thr_s;
  s1[tid] = r;
  s2[tid] = (tid < 225 && r != 0.f) ? 1.f : 0.f;
  __syncthreads();
  for (int st = 128; st > 0; st >>= 1) {
    if (tid < st) { s1[tid] += s1[tid + st]; s2[tid] += s2[tid + st]; }
    __syncthreads();
  }
  if (tid == 0) {
    float nz = s2[0] < 1.f ? 1.f : s2[0];
    thr_s = s1[0] / nz;
  }
  __syncthreads();
  float m = 0.f;
  if (tid < 225) {
    m = (r < thr_s) ? 1.f : 0.f;
    mask[(c * 4 + mi) * 225 + tid] = m;
  }
  s1[tid] = m;
  __syncthreads();
  for (int st = 128; st > 0; st >>= 1) {
    if (tid < st) s1[tid] += s1[tid + st];
    __syncthreads();
  }
  if (tid == 0) atomicAdd(&msum[c], s1[0]);
}

// ---- 7a: masked row dot products: S[c][i] = sum_col mask[c][col]*D[i,gcol] -
__global__ __launch_bounds__(256)
void contrast_rows(const float* __restrict__ D, const float* __restrict__ mask,
                   float* __restrict__ S) {
  int wave = threadIdx.x >> 6, lane = threadIdx.x & 63;
  int i = blockIdx.x * 4 + wave;
  int c = blockIdx.y;
  if (i >= NQT) return;
  const float* row = D + (size_t)i * LDD;
  const float* mk  = mask + c * 900;
  const int cbase = c * 225;
  float acc = 0.f;
#pragma unroll
  for (int k = 0; k < 15; ++k) {
    int col = k * 64 + lane;
    if (col < 900) {
      int gcol = col + (col >= cbase ? 225 : 0);
      acc += mk[col] * row[gcol];
    }
  }
#pragma unroll
  for (int s = 32; s > 0; s >>= 1) acc += __shfl_down(acc, s, 64);
  if (lane == 0) S[c * NQT + i] = acc;
}

// ---- 7b: final: dist_max + logits ------------------------------------------
__global__ void final_kernel(const float* __restrict__ S, const float* __restrict__ msum,
                             const float* __restrict__ rmax, float* __restrict__ out) {
  int gid = blockIdx.x * 256 + threadIdx.x;
  if (gid >= 375) return;
  int q = gid / 5, c = gid - q * 5;
  float dsum = 0.f, ssum = 0.f;
  for (int t = 0; t < 45; ++t) {
    dsum += rmax[c * NQT + q * 45 + t];
    ssum += S[c * NQT + q * 45 + t];
  }
  float dm = dsum / 45.f;
  float ms = msum[c]; if (ms < 1.f) ms = 1.f;
  float contrast = ssum / (ms * 180.f);   // /msum /45 /(WAY-1)
  out[q * 5 + c] = dm;
  out[375 + q * 5 + c] = dm / (contrast + dm);
}

// ---------------------------------------------------------------------------
extern "C" void kernel_launch(void* const* d_in, const int* in_sizes, int n_in,
                              void* d_out, int out_size, void* d_ws, size_t ws_size,
                              hipStream_t stream) {
  const float* support = (const float*)d_in[0];
  // d_in[1] = support_labels (arange//SHOT) -- class gather is a reshape, unused
  const float* queries = (const float*)d_in[2];
  const float* W       = (const float*)d_in[3];
  const float* bias    = (const float*)d_in[4];
  float* out = (float*)d_out;

  char* ws = (char*)d_ws;
  size_t off = 0;
  unsigned short* Ws = (unsigned short*)(ws + off); off += (size_t)4096 * 2048 * 2;  // 16.8 MB
  unsigned short* Xb = (unsigned short*)(ws + off); off += (size_t)1024 * 2048 * 2;  // 4.2 MB
  float*          Y  = (float*)(ws + off);                                           // 16.8 MB (aliased)
  float*          Dm = (float*)(ws + off);          off += (size_t)MPAD * LDD * 4;   // 21.2 MB union
  unsigned short* Eb = (unsigned short*)(ws + off); off += (size_t)MPAD * 2048 * 2;  // 18.9 MB
  float* sq      = (float*)(ws + off); off += 4608 * 4 + 256;
  float* ave     = (float*)(ws + off); off += 5 * NQT * 4 + 256;
  int*   pos     = (int*)(ws + off);   off += 5 * NQT * 4 + 256;
  float* rmax    = (float*)(ws + off); off += 5 * NQT * 4 + 256;
  float* mask    = (float*)(ws + off); off += 5 * 4 * 225 * 4 + 256;
  float* record  = (float*)(ws + off); off += 5 * 900 * 4 + 256;
  float* Sbuf    = (float*)(ws + off); off += 5 * NQT * 4 + 256;
  float* msum    = (float*)(ws + off); off += 5 * 4 + 256;

  prep<<<10258, 256, 0, stream>>>(W, queries, support, Ws, Xb, record, msum);

  dim3 g1(1024 / 128, 4096 / 128);   // 8 x 32 = 256 blocks
  gemm_bt<<<g1, 256, 0, stream>>>(Xb, Ws, 2048, 2048, 2048, 2,
                                  nullptr, Y, 4096);

  build_e<<<MPAD, 256, 0, stream>>>(Y, bias, Eb, sq);

  dim3 g2(MPAD / 128, LDD / 128);    // 36 x 9 = 324 blocks
  gemm_bt<<<g2, 256, 0, stream>>>(Eb, Eb + (size_t)NQT * 2048, K2, K2, K2, 1,
                                  sq, Dm, LDD);

  dim3 gs((NQT + 3) / 4, 5);         // 844 x 5, 1 wave per (c,row)
  stats_wave<<<gs, 256, 0, stream>>>(Dm, ave, pos, rmax);
  record_part<<<135, 256, 0, stream>>>(Dm, ave, pos, record);
  record_finish<<<20, 256, 0, stream>>>(record, mask, msum);
  dim3 gc((NQT + 3) / 4, 5);
  contrast_rows<<<gc, 256, 0, stream>>>(Dm, mask, Sbuf);
  final_kernel<<<2, 256, 0, stream>>>(Sbuf, msum, rmax, out);
}

// Round 7
// 284.863 us; speedup vs baseline: 1.0567x; 1.0567x over previous
//
#include <hip/hip_runtime.h>

// ---------------------------------------------------------------------------
// DistanceLoss pipeline on MI355X (gfx950)
//
// R4: tuple-gather factored out of embed GEMM (Y = X@Wsplit^T, 16.8 GFLOP).
// R5: contrast as per-(class,row) wave dot products.
// R6: raw s_barrier + manual vmcnt pipelining.
// R7: 5-stage LDS ring, constant vmcnt(12) (4-iter lookahead, clamped
//     prefetch keeps the loop uniform); stats_wave scratch-free (per-lane
//     scalar group-max, lane%5 ownership, intra-wave LDS reduce).
//
//  1. prep: W fp32->split bf16 [4096x2048]; X bf16 [1024x2048]; zero record/msum
//  2. gemm_bt epi=2: Y = X @ Wsplit^T, fp32 [1024x4096]
//  3. build_e: E rows (bf16) + row norms sq
//  4. gemm_bt epi=1: D[i][j] = dist(E[i],E[3375+j]) [4608x1152]
//  5. stats_wave: per-(c,i) rowmax/argmax/group-max (1 wave per row)
//  6. record_part / record_finish(+msum)
//  7. contrast_rows / final_kernel(dmax + logits)
// ---------------------------------------------------------------------------

typedef __bf16 bf16x8 __attribute__((ext_vector_type(8)));
typedef float f32x4 __attribute__((ext_vector_type(4)));

#define NQT   3375      // 75*45 query-tuple rows
#define MROWS 4500      // 3375 query rows + 1125 support rows
#define MPAD  4608      // 36 * 128
#define K2    2048
#define LDD   1152      // padded 1125 -> 9*128
#define BK    32        // K-tile; LDS stride = 32 (UNPADDED: required by global_load_lds)
#define NST   5         // pipeline stages

__constant__ int P0[45] = {0,0,0,0,0,0,0,0,0,
                           1,1,1,1,1,1,1,1,
                           2,2,2,2,2,2,2,
                           3,3,3,3,3,3,
                           4,4,4,4,4,
                           5,5,5,5,
                           6,6,6,
                           7,7,
                           8};
__constant__ int P1[45] = {1,2,3,4,5,6,7,8,9,
                           2,3,4,5,6,7,8,9,
                           3,4,5,6,7,8,9,
                           4,5,6,7,8,9,
                           5,6,7,8,9,
                           6,7,8,9,
                           7,8,9,
                           8,9,
                           9};

__device__ inline unsigned short f2b(float x) {
  __bf16 b = (__bf16)x;               // RNE
  return __builtin_bit_cast(unsigned short, b);
}
__device__ inline float b2f(unsigned int u16) {
  return __uint_as_float(u16 << 16);
}

// async global->LDS, 16B per lane; lds dest must be wave-uniform base + lane*16
__device__ __forceinline__ void gl_lds16(const unsigned short* g, unsigned short* l) {
  __builtin_amdgcn_global_load_lds(
      (__attribute__((address_space(1))) void*)(g),
      (__attribute__((address_space(3))) void*)(l),
      16, 0, 0);
}

// ---- 1: prep: conv W (split) + conv X + zero record/msum -------------------
__global__ void prep(const float* __restrict__ W, const float* __restrict__ Q,
                     const float* __restrict__ Sp,
                     unsigned short* __restrict__ Ws, unsigned short* __restrict__ X,
                     float* __restrict__ record, float* __restrict__ msum) {
  int b = blockIdx.x, tid = threadIdx.x;
  if (b < 8192) {                                    // W -> split bf16
    int i = b * 256 + tid;
    int i4 = i << 2;
    int o  = i4 >> 12;
    int k  = i4 & 4095;
    int hf = k >> 11;
    int kk = k & 2047;
    float4 v = reinterpret_cast<const float4*>(W)[i];
    ushort4 u;
    u.x = f2b(v.x); u.y = f2b(v.y); u.z = f2b(v.z); u.w = f2b(v.w);
    *reinterpret_cast<ushort4*>(Ws + (size_t)(o + hf * 2048) * 2048 + kk) = u;
  } else if (b < 10240) {                            // X = bf16(Q || S), pad 0
    int i = (b - 8192) * 256 + tid;
    ushort4 u = {0, 0, 0, 0};
    if (i < 384000) {                                // 750*2048/4
      float4 v = reinterpret_cast<const float4*>(Q)[i];
      u.x = f2b(v.x); u.y = f2b(v.y); u.z = f2b(v.z); u.w = f2b(v.w);
    } else if (i < 512000) {                         // + 250*2048/4
      float4 v = reinterpret_cast<const float4*>(Sp)[i - 384000];
      u.x = f2b(v.x); u.y = f2b(v.y); u.z = f2b(v.z); u.w = f2b(v.w);
    }
    reinterpret_cast<ushort4*>(X)[i] = u;
  } else {                                           // zero record + msum
    int i = (b - 10240) * 256 + tid;
    if (i < 4500) record[i] = 0.f;
    else if (i < 4505) msum[i - 4500] = 0.f;
  }
}

// ---- 2/4: bf16 MFMA GEMM, C = A @ B^T, 128x128 tile, BK=32 -----------------
// 5-stage pipelined global_load_lds ring; chunk-XOR swizzle in LDS.
// epi==1: Dout[row*ldd+col] = sqrt(max(0, sq[row] + sq[3375+col] - 2*acc))
// epi==2: Dout[row*ldd+col] = acc (fp32)
__global__ __launch_bounds__(256)
void gemm_bt(const unsigned short* __restrict__ A, const unsigned short* __restrict__ B,
             int K, int lda, int ldb, int epi,
             const float* __restrict__ sq,
             float* __restrict__ Dout, int ldd) {
  __shared__ unsigned short As[NST][128 * BK];   // 5 x 8 KB
  __shared__ unsigned short Bs[NST][128 * BK];
  const int tid  = threadIdx.x;
  const int wave = tid >> 6, lane = tid & 63;
  const int quad = lane >> 4, l16 = lane & 15;
  const int wm = (wave >> 1) * 64, wn = (wave & 1) * 64;
  const int m0 = blockIdx.x * 128, n0 = blockIdx.y * 128;

  f32x4 acc[4][4];
#pragma unroll
  for (int i = 0; i < 4; ++i)
#pragma unroll
    for (int j = 0; j < 4; ++j) {
      f32x4 z = {0.f, 0.f, 0.f, 0.f};
      acc[i][j] = z;
    }

  const int r0  = tid >> 2;                          // 0..63
  const int qsw = (tid & 3) ^ ((tid >> 3) & 3);      // swizzled global chunk
  const int kp0 = qsw * 8;
  const int rsw = (quad ^ ((l16 >> 1) & 3)) * 8;     // conflict-free read slot
  const unsigned short* pa0 = A + (size_t)(m0 + r0) * lda + kp0;
  const unsigned short* pa1 = A + (size_t)(m0 + r0 + 64) * lda + kp0;
  const unsigned short* pb0 = B + (size_t)(n0 + r0) * ldb + kp0;
  const unsigned short* pb1 = B + (size_t)(n0 + r0 + 64) * ldb + kp0;
  const int NKi = K / BK;

  // prefetches past the end are clamped (their stage is never read)
#define ISSUE(kk, st) do {                                         \
    int kc_ = (kk) < NKi ? (kk) : NKi - 1;                         \
    gl_lds16(pa0 + (size_t)kc_ * BK, &As[st][wave * 512]);         \
    gl_lds16(pa1 + (size_t)kc_ * BK, &As[st][2048 + wave * 512]);  \
    gl_lds16(pb0 + (size_t)kc_ * BK, &Bs[st][wave * 512]);         \
    gl_lds16(pb1 + (size_t)kc_ * BK, &Bs[st][2048 + wave * 512]);  \
  } while (0)

  ISSUE(0, 0); ISSUE(1, 1); ISSUE(2, 2); ISSUE(3, 3);
  asm volatile("s_waitcnt vmcnt(12)" ::: "memory");   // tile 0 resident
  __builtin_amdgcn_s_barrier();

  int sc = 0;
  for (int k = 0; k < NKi; ++k) {
    int sn = sc + 4; if (sn >= NST) sn -= NST;
    ISSUE(k + 4, sn);                                 // stays in flight across barrier
    bf16x8 af[4], bfr[4];
#pragma unroll
    for (int t = 0; t < 4; ++t)
      af[t] = *reinterpret_cast<const bf16x8*>(&As[sc][(wm + t * 16 + l16) * BK + rsw]);
#pragma unroll
    for (int t = 0; t < 4; ++t)
      bfr[t] = *reinterpret_cast<const bf16x8*>(&Bs[sc][(wn + t * 16 + l16) * BK + rsw]);
#pragma unroll
    for (int i = 0; i < 4; ++i)
#pragma unroll
      for (int j = 0; j < 4; ++j)
        acc[i][j] = __builtin_amdgcn_mfma_f32_16x16x32_bf16(af[i], bfr[j], acc[i][j], 0, 0, 0);
    asm volatile("s_waitcnt vmcnt(12)" ::: "memory"); // tile k+1 resident
    __builtin_amdgcn_s_barrier();
    sc = sc + 1; if (sc >= NST) sc = 0;
  }
#undef ISSUE
  asm volatile("s_waitcnt vmcnt(0)" ::: "memory");    // drain DMA before endpgm

  // epilogue: C/D layout col=lane&15, row=quad*4+reg
  if (epi == 2) {
#pragma unroll
    for (int i = 0; i < 4; ++i)
#pragma unroll
      for (int j = 0; j < 4; ++j) {
        int col = n0 + wn + j * 16 + l16;
        int rbase = m0 + wm + i * 16 + quad * 4;
        f32x4 v = acc[i][j];
#pragma unroll
        for (int r = 0; r < 4; ++r)
          Dout[(size_t)(rbase + r) * ldd + col] = v[r];
      }
  } else {
#pragma unroll
    for (int i = 0; i < 4; ++i)
#pragma unroll
      for (int j = 0; j < 4; ++j) {
        int col = n0 + wn + j * 16 + l16;
        int rbase = m0 + wm + i * 16 + quad * 4;
        float sc2 = sq[NQT + col];
        f32x4 v = acc[i][j];
#pragma unroll
        for (int r = 0; r < 4; ++r) {
          float x = sq[rbase + r] + sc2 - 2.f * v[r];
          Dout[(size_t)(rbase + r) * ldd + col] = sqrtf(fmaxf(x, 0.f));
        }
      }
  }
}

// ---- 3: E rows from Y (gather-add-relu-bf16) + row norms -------------------
__global__ void build_e(const float* __restrict__ Y, const float* __restrict__ bias,
                        unsigned short* __restrict__ E, float* __restrict__ sq) {
  int r = blockIdx.x, tid = threadIdx.x;
  if (r >= MROWS) {                    // pad rows: zeros
    uint4 z = {0, 0, 0, 0};
    reinterpret_cast<uint4*>(E + (size_t)r * 2048)[tid] = z;
    if (tid == 0) sq[r] = 0.f;
    return;
  }
  int x0, x1;
  if (r < NQT) {
    int n = r / 45, t = r - n * 45;
    x0 = n * 10 + P0[t]; x1 = n * 10 + P1[t];
  } else {
    int rr = r - NQT;
    int c = rr / 225, j = rr - c * 225;
    int sh = j / 45, t = j - sh * 45;
    int s = 750 + (c * 5 + sh) * 10;
    x0 = s + P0[t]; x1 = s + P1[t];
  }
  const float4* y0 = reinterpret_cast<const float4*>(Y + (size_t)x0 * 4096) + tid * 2;
  const float4* y1 = reinterpret_cast<const float4*>(Y + (size_t)x1 * 4096 + 2048) + tid * 2;
  const float4* bz = reinterpret_cast<const float4*>(bias) + tid * 2;
  float s = 0.f;
  unsigned short o[8];
#pragma unroll
  for (int h = 0; h < 2; ++h) {
    float4 a = y0[h], b = y1[h], c = bz[h];
    float v[4] = {a.x + b.x + c.x, a.y + b.y + c.y, a.z + b.z + c.z, a.w + b.w + c.w};
#pragma unroll
    for (int u = 0; u < 4; ++u) {
      float x = fmaxf(v[u], 0.f);
      unsigned short ob = f2b(x);
      o[h * 4 + u] = ob;
      float xr = b2f(ob);
      s += xr * xr;                    // norm from rounded value
    }
  }
  reinterpret_cast<uint4*>(E + (size_t)r * 2048)[tid] = *reinterpret_cast<uint4*>(o);
  __shared__ float red[256];
  red[tid] = s;
  __syncthreads();
  for (int st = 128; st > 0; st >>= 1) {
    if (tid < st) red[tid] += red[tid + st];
    __syncthreads();
  }
  if (tid == 0) sq[r] = red[0];
}

// ---- 5: stats, one wave per (c,i); scratch-free group maxima ---------------
// lane l<60 owns group l%5, visits j = l + 60r (r<4, j<225)
__global__ __launch_bounds__(256)
void stats_wave(const float* __restrict__ D, float* __restrict__ ave,
                int* __restrict__ pos, float* __restrict__ rmax) {
  __shared__ float sm[4][64];
  int wv = threadIdx.x >> 6, lane = threadIdx.x & 63;
  int i = blockIdx.x * 4 + wv;
  int c = blockIdx.y;
  if (i >= NQT) return;               // no block-wide barrier below (wave-local LDS)
  const float* p = D + (size_t)i * LDD + c * 225;
  float best = -1e30f; int bi = 225;
  float gm = -1e30f;
  if (lane < 60) {
#pragma unroll
    for (int r = 0; r < 4; ++r) {
      int j = lane + 60 * r;
      if (j < 225) {
        float v = p[j];
        if (v > best) { best = v; bi = j; }          // first-occurrence (j asc)
        gm = fmaxf(gm, v);
      }
    }
  }
#pragma unroll
  for (int s = 32; s > 0; s >>= 1) {
    float vv = __shfl_down(best, s, 64);
    int   ii = __shfl_down(bi,   s, 64);
    if (vv > best || (vv == best && ii < bi)) { best = vv; bi = ii; }
  }
  sm[wv][lane] = gm;
  __builtin_amdgcn_wave_barrier();
  if (lane < 5) {
    float m = -1e30f;
#pragma unroll
    for (int a = 0; a < 12; ++a) m = fmaxf(m, sm[wv][lane + 5 * a]);
    sm[wv][lane] = m;
  }
  __builtin_amdgcn_wave_barrier();
  if (lane == 0) {
    float s5 = sm[wv][0] + sm[wv][1] + sm[wv][2] + sm[wv][3] + sm[wv][4];
    ave[c * NQT + i]  = s5 * 0.2f;
    pos[c * NQT + i]  = bi;
    rmax[c * NQT + i] = best;
  }
}

// ---- 6a: record counts, parallel over query chunks -------------------------
__global__ void record_part(const float* __restrict__ D, const float* __restrict__ ave,
                            const int* __restrict__ pos, float* __restrict__ record) {
  int b = blockIdx.x;
  int c = b / 27, chunk = b - c * 27;
  int i0 = chunk * 125;
  int tid = threadIdx.x;
  __shared__ int   sp[125];
  __shared__ float sa[125];
  if (tid < 125) {
    sp[tid] = pos[c * NQT + i0 + tid];
    sa[tid] = ave[c * NQT + i0 + tid];
  }
  __syncthreads();
  float cnt[4] = {0.f, 0.f, 0.f, 0.f};
  int gcol[4];
#pragma unroll
  for (int j = 0; j < 4; ++j) {
    int col = tid + j * 256;
    gcol[j] = (col < 900) ? (col < c * 225 ? col : col + 225) : 0;
  }
  const bool act3 = (tid + 768) < 900;
  const float* Dsup = D + (size_t)(NQT + c * 225) * LDD;
  for (int ii = 0; ii < 125; ++ii) {
    const float* row = Dsup + (size_t)sp[ii] * LDD;
    float a = sa[ii];
    cnt[0] += (row[gcol[0]] > a) ? 1.f : 0.f;
    cnt[1] += (row[gcol[1]] > a) ? 1.f : 0.f;
    cnt[2] += (row[gcol[2]] > a) ? 1.f : 0.f;
    if (act3) cnt[3] += (row[gcol[3]] > a) ? 1.f : 0.f;
  }
#pragma unroll
  for (int j = 0; j < 4; ++j) {
    int col = tid + j * 256;
    if (col < 900) atomicAdd(&record[c * 900 + col], cnt[j]);
  }
}

// ---- 6b: thr + mask + msum partial ----------------------------------------
__global__ void record_finish(const float* __restrict__ record, float* __restrict__ mask,
                              float* __restrict__ msum) {
  int b = blockIdx.x;                 // 0..19
  int c = b / 4, mi = b - c * 4;
  int tid = threadIdx.x;
  float r = (tid < 225) ? record[c * 900 + mi * 225 + tid] : 0.f;
  __shared__ float s1[256], s2[256];
  __shared__ float thr_s;
  s1[tid] = r;
  s2[tid] = (tid < 225 && r != 0.f) ? 1.f : 0.f;
  __syncthreads();
  for (int st = 128; st > 0; st >>= 1) {
    if (tid < st) { s1[tid] += s1[tid + st]; s2[tid] += s2[tid + st]; }
    __syncthreads();
  }
  if (tid == 0) {
    float nz = s2[0] < 1.f ? 1.f : s2[0];
    thr_s = s1[0] / nz;
  }
  __syncthreads();
  float m = 0.f;
  if (tid < 225) {
    m = (r < thr_s) ? 1.f : 0.f;
    mask[(c * 4 + mi) * 225 + tid] = m;
  }
  s1[tid] = m;
  __syncthreads();
  for (int st = 128; st > 0; st >>= 1) {
    if (tid < st) s1[tid] += s1[tid + st];
    __syncthreads();
  }
  if (tid == 0) atomicAdd(&msum[c], s1[0]);
}

// ---- 7a: masked row dot products: S[c][i] = sum_col mask[c][col]*D[i,gcol] -
__global__ __launch_bounds__(256)
void contrast_rows(const float* __restrict__ D, const float* __restrict__ mask,
                   float* __restrict__ S) {
  int wave = threadIdx.x >> 6, lane = threadIdx.x & 63;
  int i = blockIdx.x * 4 + wave;
  int c = blockIdx.y;
  if (i >= NQT) return;
  const float* row = D + (size_t)i * LDD;
  const float* mk  = mask + c * 900;
  const int cbase = c * 225;
  float acc = 0.f;
#pragma unroll
  for (int k = 0; k < 15; ++k) {
    int col = k * 64 + lane;
    if (col < 900) {
      int gcol = col + (col >= cbase ? 225 : 0);
      acc += mk[col] * row[gcol];
    }
  }
#pragma unroll
  for (int s = 32; s > 0; s >>= 1) acc += __shfl_down(acc, s, 64);
  if (lane == 0) S[c * NQT + i] = acc;
}

// ---- 7b: final: dist_max + logits ------------------------------------------
__global__ void final_kernel(const float* __restrict__ S, const float* __restrict__ msum,
                             const float* __restrict__ rmax, float* __restrict__ out) {
  int gid = blockIdx.x * 256 + threadIdx.x;
  if (gid >= 375) return;
  int q = gid / 5, c = gid - q * 5;
  float dsum = 0.f, ssum = 0.f;
  for (int t = 0; t < 45; ++t) {
    dsum += rmax[c * NQT + q * 45 + t];
    ssum += S[c * NQT + q * 45 + t];
  }
  float dm = dsum / 45.f;
  float ms = msum[c]; if (ms < 1.f) ms = 1.f;
  float contrast = ssum / (ms * 180.f);   // /msum /45 /(WAY-1)
  out[q * 5 + c] = dm;
  out[375 + q * 5 + c] = dm / (contrast + dm);
}

// ---------------------------------------------------------------------------
extern "C" void kernel_launch(void* const* d_in, const int* in_sizes, int n_in,
                              void* d_out, int out_size, void* d_ws, size_t ws_size,
                              hipStream_t stream) {
  const float* support = (const float*)d_in[0];
  // d_in[1] = support_labels (arange//SHOT) -- class gather is a reshape, unused
  const float* queries = (const float*)d_in[2];
  const float* W       = (const float*)d_in[3];
  const float* bias    = (const float*)d_in[4];
  float* out = (float*)d_out;

  char* ws = (char*)d_ws;
  size_t off = 0;
  unsigned short* Ws = (unsigned short*)(ws + off); off += (size_t)4096 * 2048 * 2;  // 16.8 MB
  unsigned short* Xb = (unsigned short*)(ws + off); off += (size_t)1024 * 2048 * 2;  // 4.2 MB
  float*          Y  = (float*)(ws + off);                                           // 16.8 MB (aliased)
  float*          Dm = (float*)(ws + off);          off += (size_t)MPAD * LDD * 4;   // 21.2 MB union
  unsigned short* Eb = (unsigned short*)(ws + off); off += (size_t)MPAD * 2048 * 2;  // 18.9 MB
  float* sq      = (float*)(ws + off); off += 4608 * 4 + 256;
  float* ave     = (float*)(ws + off); off += 5 * NQT * 4 + 256;
  int*   pos     = (int*)(ws + off);   off += 5 * NQT * 4 + 256;
  float* rmax    = (float*)(ws + off); off += 5 * NQT * 4 + 256;
  float* mask    = (float*)(ws + off); off += 5 * 4 * 225 * 4 + 256;
  float* record  = (float*)(ws + off); off += 5 * 900 * 4 + 256;
  float* Sbuf    = (float*)(ws + off); off += 5 * NQT * 4 + 256;
  float* msum    = (float*)(ws + off); off += 5 * 4 + 256;

  prep<<<10258, 256, 0, stream>>>(W, queries, support, Ws, Xb, record, msum);

  dim3 g1(1024 / 128, 4096 / 128);   // 8 x 32 = 256 blocks
  gemm_bt<<<g1, 256, 0, stream>>>(Xb, Ws, 2048, 2048, 2048, 2,
                                  nullptr, Y, 4096);

  build_e<<<MPAD, 256, 0, stream>>>(Y, bias, Eb, sq);

  dim3 g2(MPAD / 128, LDD / 128);    // 36 x 9 = 324 blocks
  gemm_bt<<<g2, 256, 0, stream>>>(Eb, Eb + (size_t)NQT * 2048, K2, K2, K2, 1,
                                  sq, Dm, LDD);

  dim3 gs((NQT + 3) / 4, 5);         // 844 x 5, 1 wave per (c,row)
  stats_wave<<<gs, 256, 0, stream>>>(Dm, ave, pos, rmax);
  record_part<<<135, 256, 0, stream>>>(Dm, ave, pos, record);
  record_finish<<<20, 256, 0, stream>>>(record, mask, msum);
  dim3 gc((NQT + 3) / 4, 5);
  contrast_rows<<<gc, 256, 0, stream>>>(Dm, mask, Sbuf);
  final_kernel<<<2, 256, 0, stream>>>(Sbuf, msum, rmax, out);
}